// Round 12
// baseline (369.510 us; speedup 1.0000x reference)
//
#include <hip/hip_runtime.h>
#include <hip/hip_bf16.h>
#include <cstdint>

typedef unsigned short u16;
typedef unsigned int u32;
typedef __bf16 bf16x8 __attribute__((ext_vector_type(8)));
typedef float f32x4 __attribute__((ext_vector_type(4)));
typedef u16 u16x8 __attribute__((ext_vector_type(8)));

#define DEVINL __device__ __forceinline__

typedef __attribute__((address_space(1))) const u32 gbl_u32;
typedef __attribute__((address_space(3))) u32 lds_u32;

DEVINL void llds16(const void* g, void* l) {
  __builtin_amdgcn_global_load_lds((gbl_u32*)g, (lds_u32*)l, 16, 0, 0);
}

DEVINL u16 f2bf(float f) {
  union { float f; u32 i; } x; x.f = f;
  u32 r = x.i + 0x7FFFu + ((x.i >> 16) & 1u);
  return (u16)(r >> 16);
}

DEVINL float fast_tanh(float x) {
  x = fminf(10.f, fmaxf(-10.f, x));
  float e = __expf(2.f * x);
  return (e - 1.f) / (e + 1.f);
}

DEVINL bf16x8 cvt8(const float4& a, const float4& b) {
  bf16x8 r;
  r[0] = (__bf16)a.x; r[1] = (__bf16)a.y; r[2] = (__bf16)a.z; r[3] = (__bf16)a.w;
  r[4] = (__bf16)b.x; r[5] = (__bf16)b.y; r[6] = (__bf16)b.z; r[7] = (__bf16)b.w;
  return r;
}

// ---------------------------------------------------------------------------
// f32 -> bf16 convert (natural layout), 8 elems/thread
// ---------------------------------------------------------------------------
__global__ __launch_bounds__(256) void cvtk(const float* __restrict__ src,
                                            u16* __restrict__ dst, int n8) {
  int i = blockIdx.x * 256 + threadIdx.x;
  if (i >= n8) return;
  const float* s = src + (size_t)i * 8;
  *(bf16x8*)(dst + (size_t)i * 8) = cvt8(*(const float4*)s, *(const float4*)(s + 4));
}

// ---------------------------------------------------------------------------
// Weight tiler (BK=32, 128-row tiles) for gemm_nt4.
// chunk (n,h4): unit = h4*128 + ((n&127) ^ (h4<<1)); tile = (n>>7)*32 + kb
// K window = 1024 (k8 = 0..127), kb = k8>>2, h = k8&3.
// ---------------------------------------------------------------------------
__global__ __launch_bounds__(256) void tile_b(const float* __restrict__ src,
                                              int srcld, int koff,
                                              u16* __restrict__ dst, int nchunks) {
  int id = blockIdx.x * 256 + threadIdx.x;
  if (id >= nchunks) return;
  int n = id >> 7, k8 = id & 127;
  int kb = k8 >> 2, h = k8 & 3;
  int u = h * 128 + ((n & 127) ^ (h << 1));
  const float* s = src + (size_t)n * srcld + koff + k8 * 8;
  size_t dc = ((size_t)((n >> 7) * 32 + kb) * 512 + u) * 8;
  *(bf16x8*)(dst + dc) = cvt8(*(const float4*)s, *(const float4*)(s + 4));
}

// ---------------------------------------------------------------------------
// gemm_nt4: 128x128, BK=32, 4 waves (2x2), all-bf16, gll staging, 32 KB LDS
// -> ~4 blocks/CU co-residency (the m97 mechanism: cross-block overlap
// absorbs barrier drains). Loop: stage(t+1) -> vmcnt(4) -> barrier ->
// compute -> barrier. A: coalesced source map (R10): unit u <-> (row=u>>2,
// oct=(u&3)^(row&3)); frag read unit = row*4 + (h^(rl&3)) (2-way, free).
// B: pre-tiled (tile_b), contiguous 1KB per gll.
// ---------------------------------------------------------------------------
template <int NSEG, bool OUT_BF16, bool TANH>
__global__ __launch_bounds__(256) void gemm_nt4(
    const u16* __restrict__ A0, const u16* __restrict__ A1, int lda,
    const u16* __restrict__ Bt0, const u16* __restrict__ Bt1,
    const float* __restrict__ bias0, const float* __restrict__ bias1,
    void* __restrict__ Cout, int ldc) {
  __shared__ u16 As[2][4096];
  __shared__ u16 Bs[2][4096];
  const int tid = threadIdx.x, lane = tid & 63, w = tid >> 6;
  const int wr = w >> 1, wc = w & 1;
  const int NX = gridDim.x;
  const int total = NX * gridDim.y;
  const int flat = blockIdx.y * NX + blockIdx.x;
  const int wid = (flat & 7) * (total >> 3) + (flat >> 3);
  const int nb = wid % NX;
  const int n0 = nb * 128, m0 = (wid / NX) * 128;
  const int h = lane >> 4, rl = lane & 15;
  const int jA = h ^ (rl & 3);

  f32x4 acc[4][4];
#pragma unroll
  for (int i = 0; i < 4; ++i)
#pragma unroll
    for (int j = 0; j < 4; ++j) acc[i][j] = (f32x4)0.f;

  const int gb0 = w * 64, gb1 = 256 + w * 64;
  u32 asrc[2];
  {
    int u0 = gb0 + lane, u1 = gb1 + lane;
    int r0 = u0 >> 2, o0 = (u0 & 3) ^ (r0 & 3);
    int r1 = u1 >> 2, o1 = (u1 & 3) ^ (r1 & 3);
    asrc[0] = (u32)(m0 + r0) * (u32)lda + (u32)(o0 * 8);
    asrc[1] = (u32)(m0 + r1) * (u32)lda + (u32)(o1 * 8);
  }
  const int NT = NSEG * 32;

  auto stage = [&](int t, int buf) {
    const int seg = (NSEG == 2 && t >= 32) ? 1 : 0;
    const int kb = t - seg * 32, kl = kb << 5;
    {
      const u16* Bt = (seg ? Bt1 : Bt0) + ((size_t)(nb * 32 + kb) * 512) * 8;
      llds16(Bt + (size_t)(gb0 + lane) * 8, &Bs[buf][gb0 * 8]);
      llds16(Bt + (size_t)(gb1 + lane) * 8, &Bs[buf][gb1 * 8]);
    }
    {
      const u16* Ap = seg ? A1 : A0;
      llds16(Ap + (size_t)(asrc[0] + kl), &As[buf][gb0 * 8]);
      llds16(Ap + (size_t)(asrc[1] + kl), &As[buf][gb1 * 8]);
    }
  };
  auto compute = [&](int buf) {
    bf16x8 af[4], bfv[4];
#pragma unroll
    for (int i = 0; i < 4; ++i)
      af[i] = *(const bf16x8*)&As[buf][((wr * 64 + i * 16 + rl) * 4 + jA) * 8];
#pragma unroll
    for (int j = 0; j < 4; ++j)
      bfv[j] = *(const bf16x8*)&Bs[buf][(h * 128 + ((wc * 64 + j * 16 + rl) ^ (h << 1))) * 8];
#pragma unroll
    for (int i = 0; i < 4; ++i)
#pragma unroll
      for (int j = 0; j < 4; ++j)
        acc[i][j] =
            __builtin_amdgcn_mfma_f32_16x16x32_bf16(af[i], bfv[j], acc[i][j], 0, 0, 0);
  };

  stage(0, 0);
  for (int t = 0; t < NT; ++t) {
    const int c = t & 1;
    if (t + 1 < NT) {
      stage(t + 1, c ^ 1);  // 4 glls for t+1 stay in flight across barriers
      asm volatile("s_waitcnt vmcnt(4)" ::: "memory");
    } else {
      asm volatile("s_waitcnt vmcnt(0)" ::: "memory");
    }
    __builtin_amdgcn_s_barrier();
    __builtin_amdgcn_sched_barrier(0);
    compute(c);
    __builtin_amdgcn_s_barrier();
  }

  const int rq = lane >> 4;
#pragma unroll
  for (int j = 0; j < 4; ++j) {
    const int gc = n0 + wc * 64 + j * 16 + rl;
    float bia = 0.f;
    if (bias0) bia += bias0[gc];
    if (NSEG == 2 && bias1) bia += bias1[gc];
#pragma unroll
    for (int i = 0; i < 4; ++i) {
#pragma unroll
      for (int r = 0; r < 4; ++r) {
        const int grow = m0 + wr * 64 + i * 16 + rq * 4 + r;
        float v = acc[i][j][r] + bia;
        if (TANH) v = fast_tanh(v);
        if (OUT_BF16)
          ((u16*)Cout)[(size_t)grow * ldc + gc] = f2bf(v);
        else
          ((float*)Cout)[(size_t)grow * ldc + gc] = v;
      }
    }
  }
}

// ---------------------------------------------------------------------------
// NN GEMM (per batch): mix[l,d] = sum_w alpha[l,w]*ctx_bf[w,d]; K=512.
// ---------------------------------------------------------------------------
__global__ __launch_bounds__(256) void gemm_nn3(
    const float* __restrict__ alpha, const u16* __restrict__ ctxb,
    u16* __restrict__ mix) {
  __shared__ u16 As[2][4096];
  __shared__ u16 Bs[2][4096];
  const int tid = threadIdx.x, lane = tid & 63, w = tid >> 6;
  const int wr = w >> 1, wc = w & 1;
  const int b = blockIdx.z;
  const int n0 = blockIdx.x * 128, m0 = blockIdx.y * 128;
  const int h = lane >> 4, rlx = (lane & 15) ^ (h << 1);
  const float* A = alpha + (size_t)b * 262144;
  u16* C = mix + (size_t)b * 524288;

  f32x4 acc[4][4];
#pragma unroll
  for (int i = 0; i < 4; ++i)
#pragma unroll
    for (int j = 0; j < 4; ++j) acc[i][j] = (f32x4)0.f;

  const int row0 = tid >> 2, cb = tid & 3, row1 = 64 + row0;
  const int unit0 = cb * 128 + (row0 ^ (cb << 1));
  const int unit1 = cb * 128 + (row1 ^ (cb << 1));
  const int kl = tid & 31, ng = tid >> 5;
  const int hb = kl >> 3, kp = kl & 7;

  float4 fr[4];
  u16x8 ub[2];

  auto stage = [&](int t) {
    const int k0 = t << 5;
    const float* p0 = A + (size_t)(m0 + row0) * 512 + k0 + cb * 8;
    const float* p1 = A + (size_t)(m0 + row1) * 512 + k0 + cb * 8;
    fr[0] = *(const float4*)p0; fr[1] = *(const float4*)(p0 + 4);
    fr[2] = *(const float4*)p1; fr[3] = *(const float4*)(p1 + 4);
    const u16* Cb = ctxb + (size_t)b * 524288 + (size_t)(k0 + kl) * 1024 +
                    n0 + ng * 16;
    ub[0] = *(const u16x8*)Cb; ub[1] = *(const u16x8*)(Cb + 8);
  };
  auto stage_fin = [&](int buf) {
    *(bf16x8*)&As[buf][unit0 * 8] = cvt8(fr[0], fr[1]);
    *(bf16x8*)&As[buf][unit1 * 8] = cvt8(fr[2], fr[3]);
#pragma unroll
    for (int j = 0; j < 16; ++j) {
      int n = ng * 16 + j;
      Bs[buf][(hb * 128 + (n ^ (hb << 1))) * 8 + kp] =
          (j < 8) ? ub[0][j] : ub[1][j - 8];
    }
  };
  auto compute = [&](int buf) {
    bf16x8 af[4], bfv[4];
#pragma unroll
    for (int i = 0; i < 4; ++i)
      af[i] = *(const bf16x8*)&As[buf][(h * 128 + wr * 64 + i * 16 + rlx) * 8];
#pragma unroll
    for (int j = 0; j < 4; ++j)
      bfv[j] = *(const bf16x8*)&Bs[buf][(h * 128 + wc * 64 + j * 16 + rlx) * 8];
#pragma unroll
    for (int i = 0; i < 4; ++i)
#pragma unroll
      for (int j = 0; j < 4; ++j)
        acc[i][j] =
            __builtin_amdgcn_mfma_f32_16x16x32_bf16(af[i], bfv[j], acc[i][j], 0, 0, 0);
  };

  stage(0);
  stage_fin(0);
  __syncthreads();
  for (int t = 0; t < 16; ++t) {
    const int cb_ = t & 1;
    if (t + 1 < 16) stage(t + 1);
    compute(cb_);
    if (t + 1 < 16) stage_fin(cb_ ^ 1);
    __syncthreads();
  }

  const int rl = lane & 15, rq = lane >> 4;
#pragma unroll
  for (int j = 0; j < 4; ++j) {
    const int gc = n0 + wc * 64 + j * 16 + rl;
#pragma unroll
    for (int i = 0; i < 4; ++i) {
#pragma unroll
      for (int r = 0; r < 4; ++r) {
        const int grow = m0 + wr * 64 + i * 16 + rq * 4 + r;
        C[(size_t)grow * 1024 + gc] = f2bf(acc[i][j][r]);
      }
    }
  }
}

// ---------------------------------------------------------------------------
// Row softmax, in-place f32: one wave per row of 512
// ---------------------------------------------------------------------------
__global__ __launch_bounds__(256) void softmax_rows_f32(float* __restrict__ S) {
  const int row = blockIdx.x * 4 + (threadIdx.x >> 6);
  const int lane = threadIdx.x & 63;
  float* s = S + (size_t)row * 512 + lane * 8;
  float4 v0 = *(const float4*)s;
  float4 v1 = *(const float4*)(s + 4);
  float vs[8] = {v0.x, v0.y, v0.z, v0.w, v1.x, v1.y, v1.z, v1.w};
  float vm = vs[0];
#pragma unroll
  for (int j = 1; j < 8; ++j) vm = fmaxf(vm, vs[j]);
#pragma unroll
  for (int off = 32; off > 0; off >>= 1) vm = fmaxf(vm, __shfl_xor(vm, off, 64));
  float e[8];
  float sum = 0.f;
#pragma unroll
  for (int j = 0; j < 8; ++j) { e[j] = __expf(vs[j] - vm); sum += e[j]; }
#pragma unroll
  for (int off = 32; off > 0; off >>= 1) sum += __shfl_xor(sum, off, 64);
  float inv = 1.f / sum;
  float4 o0 = {e[0] * inv, e[1] * inv, e[2] * inv, e[3] * inv};
  float4 o1 = {e[4] * inv, e[5] * inv, e[6] * inv, e[7] * inv};
  *(float4*)s = o0;
  *(float4*)(s + 4) = o1;
}

// ---------------------------------------------------------------------------
extern "C" void kernel_launch(void* const* d_in, const int* in_sizes, int n_in,
                              void* d_out, int out_size, void* d_ws, size_t ws_size,
                              hipStream_t stream) {
  const float* query = (const float*)d_in[0];  // [32,512,1024] f32
  const float* ctx   = (const float*)d_in[1];  // [32,512,1024]
  const float* W_in  = (const float*)d_in[2];  // [1024,1024]
  const float* b_in  = (const float*)d_in[3];  // [1024]
  const float* W_in2 = (const float*)d_in[4];  // [1024,1024]
  const float* b_in2 = (const float*)d_in[5];  // [1024]
  const float* W_out = (const float*)d_in[6];  // [512,1024]
  const float* W_fc  = (const float*)d_in[7];  // [1024,2048]
  const float* b_fc  = (const float*)d_in[8];  // [1024]

  float* out   = (float*)d_out;               // [32*512*1024] f32
  float* alpha = (float*)d_out + 16777216;    // [32*512*512] f32 (scores too)

  // ws: [weights 9MB][t/mix 33.5MB][cbf 33.5MB][qbf 33.5MB]
  u16* wibf_t  = (u16*)d_ws;                 // 1048576 (tile_b layout)
  u16* wi2bf_t = wibf_t + 1048576;           // 1048576
  u16* wobf_t  = wibf_t + 2097152;           // 524288
  u16* wf0_t   = wibf_t + 2621440;           // 1048576
  u16* wf1_t   = wibf_t + 3670016;           // 1048576
  u16* t_ws    = (u16*)((char*)d_ws + 9437184);
  u16* cbf     = (u16*)((char*)d_ws + 42991616);
  u16* qbf     = (u16*)((char*)d_ws + 76546048);

  dim3 blk(256, 1, 1);

  // K0: tile/convert weights + activations (all weights in tile_b layout)
  tile_b<<<dim3(512), blk, 0, stream>>>(W_in, 1024, 0, wibf_t, 131072);
  tile_b<<<dim3(512), blk, 0, stream>>>(W_in2, 1024, 0, wi2bf_t, 131072);
  tile_b<<<dim3(256), blk, 0, stream>>>(W_out, 1024, 0, wobf_t, 65536);
  tile_b<<<dim3(512), blk, 0, stream>>>(W_fc, 2048, 0, wf0_t, 131072);
  tile_b<<<dim3(512), blk, 0, stream>>>(W_fc, 2048, 1024, wf1_t, 131072);
  cvtk<<<dim3(8192), blk, 0, stream>>>(ctx, cbf, 2097152);
  cvtk<<<dim3(8192), blk, 0, stream>>>(query, qbf, 2097152);

  // K1: t = tanh(query@W_in^T + ctx@W_in2^T + b_in + b_in2) -> bf16
  gemm_nt4<2, true, true><<<dim3(8, 128), blk, 0, stream>>>(
      qbf, cbf, 1024, wibf_t, wi2bf_t, b_in, b_in2, t_ws, 1024);

  // K2: scores = t @ W_out^T -> f32 into alpha slot
  gemm_nt4<1, false, false><<<dim3(4, 128), blk, 0, stream>>>(
      t_ws, nullptr, 1024, wobf_t, nullptr, nullptr, nullptr, alpha, 512);

  // K3: softmax in-place
  softmax_rows_f32<<<dim3(4096), blk, 0, stream>>>(alpha);

  // K4: mix = alpha @ ctx -> bf16 (t region; t dead after K2)
  gemm_nn3<<<dim3(8, 4, 32), blk, 0, stream>>>(alpha, cbf, t_ws);

  // K5: out = mix@W_fc[:, :1024]^T + ctx@W_fc[:, 1024:]^T + b_fc -> f32
  gemm_nt4<2, false, false><<<dim3(8, 128), blk, 0, stream>>>(
      t_ws, cbf, 1024, wf0_t, wf1_t, b_fc, nullptr, out, 1024);
}

// Round 13
// 285.908 us; speedup vs baseline: 1.2924x; 1.2924x over previous
//
#include <hip/hip_runtime.h>
#include <hip/hip_bf16.h>
#include <cstdint>

typedef unsigned short u16;
typedef unsigned int u32;
typedef __bf16 bf16x8 __attribute__((ext_vector_type(8)));
typedef float f32x4 __attribute__((ext_vector_type(4)));
typedef u16 u16x8 __attribute__((ext_vector_type(8)));

#define DEVINL __device__ __forceinline__

typedef __attribute__((address_space(1))) const u32 gbl_u32;
typedef __attribute__((address_space(3))) u32 lds_u32;

DEVINL void llds16(const void* g, void* l) {
  __builtin_amdgcn_global_load_lds((gbl_u32*)g, (lds_u32*)l, 16, 0, 0);
}

DEVINL u16 f2bf(float f) {
  union { float f; u32 i; } x; x.f = f;
  u32 r = x.i + 0x7FFFu + ((x.i >> 16) & 1u);
  return (u16)(r >> 16);
}

DEVINL float fast_tanh(float x) {
  x = fminf(10.f, fmaxf(-10.f, x));
  float e = __expf(2.f * x);
  return (e - 1.f) / (e + 1.f);
}

DEVINL bf16x8 cvt8(const float4& a, const float4& b) {
  bf16x8 r;
  r[0] = (__bf16)a.x; r[1] = (__bf16)a.y; r[2] = (__bf16)a.z; r[3] = (__bf16)a.w;
  r[4] = (__bf16)b.x; r[5] = (__bf16)b.y; r[6] = (__bf16)b.z; r[7] = (__bf16)b.w;
  return r;
}

// ---------------------------------------------------------------------------
// f32 -> bf16 convert (natural layout), 8 elems/thread
// ---------------------------------------------------------------------------
__global__ __launch_bounds__(256) void cvtk(const float* __restrict__ src,
                                            u16* __restrict__ dst, int n8) {
  int i = blockIdx.x * 256 + threadIdx.x;
  if (i >= n8) return;
  const float* s = src + (size_t)i * 8;
  *(bf16x8*)(dst + (size_t)i * 8) = cvt8(*(const float4*)s, *(const float4*)(s + 4));
}

// ---------------------------------------------------------------------------
// Weight tiler (BK=32, 128-row tiles) for gemm_nt4 (K2 / W_out).
// ---------------------------------------------------------------------------
__global__ __launch_bounds__(256) void tile_b(const float* __restrict__ src,
                                              int srcld, int koff,
                                              u16* __restrict__ dst, int nchunks) {
  int id = blockIdx.x * 256 + threadIdx.x;
  if (id >= nchunks) return;
  int n = id >> 7, k8 = id & 127;
  int kb = k8 >> 2, h = k8 & 3;
  int u = h * 128 + ((n & 127) ^ (h << 1));
  const float* s = src + (size_t)n * srcld + koff + k8 * 8;
  size_t dc = ((size_t)((n >> 7) * 32 + kb) * 512 + u) * 8;
  *(bf16x8*)(dst + dc) = cvt8(*(const float4*)s, *(const float4*)(s + 4));
}

// ---------------------------------------------------------------------------
// Weight tiler (BK=64, 256-row tiles) for gemm_nt9 B-side.
// chunk (n, h=k8&7): unit = h*256 + ((n&255) ^ (h<<1)); tile = (n>>8)*16 + kb
// ---------------------------------------------------------------------------
__global__ __launch_bounds__(256) void tile_b64(const float* __restrict__ src,
                                                int srcld, int koff,
                                                u16* __restrict__ dst, int nchunks) {
  int id = blockIdx.x * 256 + threadIdx.x;
  if (id >= nchunks) return;
  int n = id >> 7, k8 = id & 127;
  int kb = k8 >> 3, h = k8 & 7;
  int u = h * 256 + ((n & 255) ^ (h << 1));
  const float* s = src + (size_t)n * srcld + koff + k8 * 8;
  size_t dc = ((size_t)((n >> 8) * 16 + kb) * 2048 + u) * 8;
  *(bf16x8*)(dst + dc) = cvt8(*(const float4*)s, *(const float4*)(s + 4));
}

// ---------------------------------------------------------------------------
// gemm_nt9: 256x256, BK=64, 8 waves (2Mx4N), all-bf16, gll staging.
// DEPTH-CORRECT pipeline: A triple-buffered (As[3]), B double (Bs[2]);
// per tile t: Ph0 {top-guard vmcnt(6)+bar; read kh0; stage B[t+1]; 32 MFMA}
//             Ph1 {mid-guard vmcnt(8)+bar; read kh1; stage A[t+2]; 32 MFMA}
// FIFO issue order B[t+1],A[t+2] matches consumption (B 1 tile ahead,
// A 2 tiles ahead -> ~3.5 phases slack, HBM-proof). Guards sit at the
// consumption barrier, never earlier. LDS = 3*32K + 2*32K = 160 KB.
// A map (coalesced src, 2-way-free read): unit u <-> (row=u>>3,
// oct=(u&7)^(row&7)). B: pre-tiled (tile_b64), contiguous 1KB per gll.
// ---------------------------------------------------------------------------
template <int NSEG, bool OUT_BF16, bool TANH>
__global__ __launch_bounds__(512) void gemm_nt9(
    const u16* __restrict__ A0, const u16* __restrict__ A1,
    const u16* __restrict__ Bt0, const u16* __restrict__ Bt1,
    const float* __restrict__ bias0, const float* __restrict__ bias1,
    void* __restrict__ Cout, int ldc) {
  __shared__ u16 As[3][16384];
  __shared__ u16 Bs[2][16384];
  const int tid = threadIdx.x, lane = tid & 63, w = tid >> 6;
  const int wr = w >> 2, wc = w & 3;

  // XCD-bijective swizzle (total % 8 == 0)
  const int NX = gridDim.x;
  const int total = NX * gridDim.y;
  const int flat = blockIdx.y * NX + blockIdx.x;
  const int wid = (flat & 7) * (total >> 3) + (flat >> 3);
  const int nb = wid % NX;
  const int n0 = nb * 256, m0 = (wid / NX) * 256;

  f32x4 acc[8][4];
#pragma unroll
  for (int i = 0; i < 8; ++i)
#pragma unroll
    for (int j = 0; j < 4; ++j) acc[i][j] = (f32x4)0.f;

  // staging maps (quarter q = units [q*512, q*512+512))
  u32 asrc[4], bofs[4];
#pragma unroll
  for (int r = 0; r < 4; ++r) {
    int u = r * 512 + w * 64 + lane;
    int row = u >> 3, oct = (u & 7) ^ (row & 7);
    asrc[r] = (u32)(m0 + row) * 1024u + (u32)(oct * 8);
    bofs[r] = (u32)u * 8u;
  }

  const int NT = NSEG * 16;

  auto stageA = [&](int t) {  // 4 glls into As[t%3]
    const int seg = (NSEG == 2 && t >= 16) ? 1 : 0;
    const int kb = t - (seg << 4);
    const u16* Ap = seg ? A1 : A0;
    const u32 k0 = (u32)(kb << 6);
    u16* dst = As[t % 3];
#pragma unroll
    for (int q = 0; q < 4; ++q)
      llds16(Ap + (size_t)(asrc[q] + k0), dst + (q * 512 + w * 64) * 8);
  };
  auto stageB = [&](int t) {  // 4 glls into Bs[t&1]
    const int seg = (NSEG == 2 && t >= 16) ? 1 : 0;
    const int kb = t - (seg << 4);
    const u16* Bt = (seg ? Bt1 : Bt0) + ((size_t)(nb * 16 + kb) << 14);
    u16* dst = Bs[t & 1];
#pragma unroll
    for (int q = 0; q < 4; ++q)
      llds16(Bt + (size_t)bofs[q], dst + (q * 512 + w * 64) * 8);
  };

  // prologue: FIFO = A0(4), B0(4), A1(4)  [steady-state shape from t=0]
  stageA(0);
  stageB(0);
  if (NT > 1) stageA(1);

  const int rl = lane & 15;
  for (int t = 0; t < NT; ++t) {
    const int ab = t % 3, bb = t & 1;
    const bool preB = (t + 1 < NT);
    const bool preA = (t + 2 < NT);

    // ---- top-of-tile guard: A[t] + B q01[t] landed ----
    if (preB) asm volatile("s_waitcnt vmcnt(6)" ::: "memory");
    else      asm volatile("s_waitcnt vmcnt(2)" ::: "memory");
    __builtin_amdgcn_s_barrier();
    __builtin_amdgcn_sched_barrier(0);
    {  // Ph0: kh0 (B q01)
      const int h = lane >> 4;
      const int jA = h ^ (rl & 7);
      bf16x8 af[8], bv[4];
#pragma unroll
      for (int i = 0; i < 8; ++i)
        af[i] = *(const bf16x8*)&As[ab][((wr * 128 + i * 16 + rl) * 8 + jA) * 8];
#pragma unroll
      for (int j = 0; j < 4; ++j)
        bv[j] = *(const bf16x8*)&Bs[bb][(h * 256 + ((wc * 64 + j * 16 + rl) ^ (h << 1))) * 8];
      if (preB) stageB(t + 1);
      __builtin_amdgcn_s_setprio(1);
#pragma unroll
      for (int i = 0; i < 8; ++i)
#pragma unroll
        for (int j = 0; j < 4; ++j)
          acc[i][j] =
              __builtin_amdgcn_mfma_f32_16x16x32_bf16(af[i], bv[j], acc[i][j], 0, 0, 0);
      __builtin_amdgcn_s_setprio(0);
    }
    // ---- mid-tile guard: B q23[t] landed ----
    if (preB) asm volatile("s_waitcnt vmcnt(8)" ::: "memory");
    else      asm volatile("s_waitcnt vmcnt(0)" ::: "memory");
    __builtin_amdgcn_s_barrier();
    __builtin_amdgcn_sched_barrier(0);
    {  // Ph1: kh1 (B q23)
      const int h = 4 + (lane >> 4);
      const int jA = h ^ (rl & 7);
      bf16x8 af[8], bv[4];
#pragma unroll
      for (int i = 0; i < 8; ++i)
        af[i] = *(const bf16x8*)&As[ab][((wr * 128 + i * 16 + rl) * 8 + jA) * 8];
#pragma unroll
      for (int j = 0; j < 4; ++j)
        bv[j] = *(const bf16x8*)&Bs[bb][(h * 256 + ((wc * 64 + j * 16 + rl) ^ (h << 1))) * 8];
      if (preA) stageA(t + 2);
      __builtin_amdgcn_s_setprio(1);
#pragma unroll
      for (int i = 0; i < 8; ++i)
#pragma unroll
        for (int j = 0; j < 4; ++j)
          acc[i][j] =
              __builtin_amdgcn_mfma_f32_16x16x32_bf16(af[i], bv[j], acc[i][j], 0, 0, 0);
      __builtin_amdgcn_s_setprio(0);
    }
  }

  // Epilogue. C/D: col = lane&15, row = (lane>>4)*4 + reg.
  const int rq = lane >> 4;
#pragma unroll
  for (int j = 0; j < 4; ++j) {
    const int gc = n0 + wc * 64 + j * 16 + rl;
    float bia = 0.f;
    if (bias0) bia += bias0[gc];
    if (NSEG == 2 && bias1) bia += bias1[gc];
#pragma unroll
    for (int i = 0; i < 8; ++i) {
#pragma unroll
      for (int r = 0; r < 4; ++r) {
        const int grow = m0 + wr * 128 + i * 16 + rq * 4 + r;
        float v = acc[i][j][r] + bia;
        if (TANH) v = fast_tanh(v);
        if (OUT_BF16)
          ((u16*)Cout)[(size_t)grow * ldc + gc] = f2bf(v);
        else
          ((float*)Cout)[(size_t)grow * ldc + gc] = v;
      }
    }
  }
}

// ---------------------------------------------------------------------------
// gemm_nt4: 128x128/BK=32 all-bf16 (K2 only). R10/R11 version.
// ---------------------------------------------------------------------------
template <int NSEG, bool OUT_BF16, bool TANH>
__global__ __launch_bounds__(256) void gemm_nt4(
    const u16* __restrict__ A0, const u16* __restrict__ A1, int lda,
    const u16* __restrict__ Bt0, const u16* __restrict__ Bt1,
    const float* __restrict__ bias0, const float* __restrict__ bias1,
    void* __restrict__ Cout, int ldc) {
  __shared__ u16 As[2][4096];
  __shared__ u16 Bs[2][4096];
  const int tid = threadIdx.x, lane = tid & 63, w = tid >> 6;
  const int wr = w >> 1, wc = w & 1;
  const int NX = gridDim.x;
  const int total = NX * gridDim.y;
  const int flat = blockIdx.y * NX + blockIdx.x;
  const int wid = (flat & 7) * (total >> 3) + (flat >> 3);
  const int nb = wid % NX;
  const int n0 = nb * 128, m0 = (wid / NX) * 128;
  const int h = lane >> 4, rl = lane & 15;
  const int jA = h ^ (rl & 3);

  f32x4 acc[4][4];
#pragma unroll
  for (int i = 0; i < 4; ++i)
#pragma unroll
    for (int j = 0; j < 4; ++j) acc[i][j] = (f32x4)0.f;

  const int gb0 = w * 64, gb1 = 256 + w * 64;
  u32 asrc[2];
  {
    int u0 = gb0 + lane, u1 = gb1 + lane;
    int r0 = u0 >> 2, o0 = (u0 & 3) ^ (r0 & 3);
    int r1 = u1 >> 2, o1 = (u1 & 3) ^ (r1 & 3);
    asrc[0] = (u32)(m0 + r0) * (u32)lda + (u32)(o0 * 8);
    asrc[1] = (u32)(m0 + r1) * (u32)lda + (u32)(o1 * 8);
  }
  const int NT = NSEG * 32;

  auto stage = [&](int t, int buf) {
    const int seg = (NSEG == 2 && t >= 32) ? 1 : 0;
    const int kb = t - seg * 32, kl = kb << 5;
    {
      const u16* Bt = (seg ? Bt1 : Bt0) + ((size_t)(nb * 32 + kb) * 512) * 8;
      llds16(Bt + (size_t)(gb0 + lane) * 8, &Bs[buf][gb0 * 8]);
      llds16(Bt + (size_t)(gb1 + lane) * 8, &Bs[buf][gb1 * 8]);
    }
    {
      const u16* Ap = seg ? A1 : A0;
      llds16(Ap + (size_t)(asrc[0] + kl), &As[buf][gb0 * 8]);
      llds16(Ap + (size_t)(asrc[1] + kl), &As[buf][gb1 * 8]);
    }
  };
  auto compute = [&](int buf) {
    bf16x8 af[4], bfv[4];
#pragma unroll
    for (int i = 0; i < 4; ++i)
      af[i] = *(const bf16x8*)&As[buf][((wr * 64 + i * 16 + rl) * 4 + jA) * 8];
#pragma unroll
    for (int j = 0; j < 4; ++j)
      bfv[j] = *(const bf16x8*)&Bs[buf][(h * 128 + ((wc * 64 + j * 16 + rl) ^ (h << 1))) * 8];
#pragma unroll
    for (int i = 0; i < 4; ++i)
#pragma unroll
      for (int j = 0; j < 4; ++j)
        acc[i][j] =
            __builtin_amdgcn_mfma_f32_16x16x32_bf16(af[i], bfv[j], acc[i][j], 0, 0, 0);
  };

  stage(0, 0);
  for (int t = 0; t < NT; ++t) {
    const int c = t & 1;
    if (t + 1 < NT) {
      stage(t + 1, c ^ 1);
      asm volatile("s_waitcnt vmcnt(4)" ::: "memory");
    } else {
      asm volatile("s_waitcnt vmcnt(0)" ::: "memory");
    }
    __builtin_amdgcn_s_barrier();
    __builtin_amdgcn_sched_barrier(0);
    compute(c);
    __builtin_amdgcn_s_barrier();
  }

  const int rq = lane >> 4;
#pragma unroll
  for (int j = 0; j < 4; ++j) {
    const int gc = n0 + wc * 64 + j * 16 + rl;
    float bia = 0.f;
    if (bias0) bia += bias0[gc];
    if (NSEG == 2 && bias1) bia += bias1[gc];
#pragma unroll
    for (int i = 0; i < 4; ++i) {
#pragma unroll
      for (int r = 0; r < 4; ++r) {
        const int grow = m0 + wr * 64 + i * 16 + rq * 4 + r;
        float v = acc[i][j][r] + bia;
        if (TANH) v = fast_tanh(v);
        if (OUT_BF16)
          ((u16*)Cout)[(size_t)grow * ldc + gc] = f2bf(v);
        else
          ((float*)Cout)[(size_t)grow * ldc + gc] = v;
      }
    }
  }
}

// ---------------------------------------------------------------------------
// NN GEMM (per batch): mix[l,d] = sum_w alpha[l,w]*ctx_bf[w,d]; K=512.
// ---------------------------------------------------------------------------
__global__ __launch_bounds__(256) void gemm_nn3(
    const float* __restrict__ alpha, const u16* __restrict__ ctxb,
    u16* __restrict__ mix) {
  __shared__ u16 As[2][4096];
  __shared__ u16 Bs[2][4096];
  const int tid = threadIdx.x, lane = tid & 63, w = tid >> 6;
  const int wr = w >> 1, wc = w & 1;
  const int b = blockIdx.z;
  const int n0 = blockIdx.x * 128, m0 = blockIdx.y * 128;
  const int h = lane >> 4, rlx = (lane & 15) ^ (h << 1);
  const float* A = alpha + (size_t)b * 262144;
  u16* C = mix + (size_t)b * 524288;

  f32x4 acc[4][4];
#pragma unroll
  for (int i = 0; i < 4; ++i)
#pragma unroll
    for (int j = 0; j < 4; ++j) acc[i][j] = (f32x4)0.f;

  const int row0 = tid >> 2, cb = tid & 3, row1 = 64 + row0;
  const int unit0 = cb * 128 + (row0 ^ (cb << 1));
  const int unit1 = cb * 128 + (row1 ^ (cb << 1));
  const int kl = tid & 31, ng = tid >> 5;
  const int hb = kl >> 3, kp = kl & 7;

  float4 fr[4];
  u16x8 ub[2];

  auto stage = [&](int t) {
    const int k0 = t << 5;
    const float* p0 = A + (size_t)(m0 + row0) * 512 + k0 + cb * 8;
    const float* p1 = A + (size_t)(m0 + row1) * 512 + k0 + cb * 8;
    fr[0] = *(const float4*)p0; fr[1] = *(const float4*)(p0 + 4);
    fr[2] = *(const float4*)p1; fr[3] = *(const float4*)(p1 + 4);
    const u16* Cb = ctxb + (size_t)b * 524288 + (size_t)(k0 + kl) * 1024 +
                    n0 + ng * 16;
    ub[0] = *(const u16x8*)Cb; ub[1] = *(const u16x8*)(Cb + 8);
  };
  auto stage_fin = [&](int buf) {
    *(bf16x8*)&As[buf][unit0 * 8] = cvt8(fr[0], fr[1]);
    *(bf16x8*)&As[buf][unit1 * 8] = cvt8(fr[2], fr[3]);
#pragma unroll
    for (int j = 0; j < 16; ++j) {
      int n = ng * 16 + j;
      Bs[buf][(hb * 128 + (n ^ (hb << 1))) * 8 + kp] =
          (j < 8) ? ub[0][j] : ub[1][j - 8];
    }
  };
  auto compute = [&](int buf) {
    bf16x8 af[4], bfv[4];
#pragma unroll
    for (int i = 0; i < 4; ++i)
      af[i] = *(const bf16x8*)&As[buf][(h * 128 + wr * 64 + i * 16 + rlx) * 8];
#pragma unroll
    for (int j = 0; j < 4; ++j)
      bfv[j] = *(const bf16x8*)&Bs[buf][(h * 128 + wc * 64 + j * 16 + rlx) * 8];
#pragma unroll
    for (int i = 0; i < 4; ++i)
#pragma unroll
      for (int j = 0; j < 4; ++j)
        acc[i][j] =
            __builtin_amdgcn_mfma_f32_16x16x32_bf16(af[i], bfv[j], acc[i][j], 0, 0, 0);
  };

  stage(0);
  stage_fin(0);
  __syncthreads();
  for (int t = 0; t < 16; ++t) {
    const int cb_ = t & 1;
    if (t + 1 < 16) stage(t + 1);
    compute(cb_);
    if (t + 1 < 16) stage_fin(cb_ ^ 1);
    __syncthreads();
  }

  const int rl = lane & 15, rq = lane >> 4;
#pragma unroll
  for (int j = 0; j < 4; ++j) {
    const int gc = n0 + wc * 64 + j * 16 + rl;
#pragma unroll
    for (int i = 0; i < 4; ++i) {
#pragma unroll
      for (int r = 0; r < 4; ++r) {
        const int grow = m0 + wr * 64 + i * 16 + rq * 4 + r;
        C[(size_t)grow * 1024 + gc] = f2bf(acc[i][j][r]);
      }
    }
  }
}

// ---------------------------------------------------------------------------
// Row softmax, in-place f32: one wave per row of 512
// ---------------------------------------------------------------------------
__global__ __launch_bounds__(256) void softmax_rows_f32(float* __restrict__ S) {
  const int row = blockIdx.x * 4 + (threadIdx.x >> 6);
  const int lane = threadIdx.x & 63;
  float* s = S + (size_t)row * 512 + lane * 8;
  float4 v0 = *(const float4*)s;
  float4 v1 = *(const float4*)(s + 4);
  float vs[8] = {v0.x, v0.y, v0.z, v0.w, v1.x, v1.y, v1.z, v1.w};
  float vm = vs[0];
#pragma unroll
  for (int j = 1; j < 8; ++j) vm = fmaxf(vm, vs[j]);
#pragma unroll
  for (int off = 32; off > 0; off >>= 1) vm = fmaxf(vm, __shfl_xor(vm, off, 64));
  float e[8];
  float sum = 0.f;
#pragma unroll
  for (int j = 0; j < 8; ++j) { e[j] = __expf(vs[j] - vm); sum += e[j]; }
#pragma unroll
  for (int off = 32; off > 0; off >>= 1) sum += __shfl_xor(sum, off, 64);
  float inv = 1.f / sum;
  float4 o0 = {e[0] * inv, e[1] * inv, e[2] * inv, e[3] * inv};
  float4 o1 = {e[4] * inv, e[5] * inv, e[6] * inv, e[7] * inv};
  *(float4*)s = o0;
  *(float4*)(s + 4) = o1;
}

// ---------------------------------------------------------------------------
extern "C" void kernel_launch(void* const* d_in, const int* in_sizes, int n_in,
                              void* d_out, int out_size, void* d_ws, size_t ws_size,
                              hipStream_t stream) {
  const float* query = (const float*)d_in[0];  // [32,512,1024] f32
  const float* ctx   = (const float*)d_in[1];  // [32,512,1024]
  const float* W_in  = (const float*)d_in[2];  // [1024,1024]
  const float* b_in  = (const float*)d_in[3];  // [1024]
  const float* W_in2 = (const float*)d_in[4];  // [1024,1024]
  const float* b_in2 = (const float*)d_in[5];  // [1024]
  const float* W_out = (const float*)d_in[6];  // [512,1024]
  const float* W_fc  = (const float*)d_in[7];  // [1024,2048]
  const float* b_fc  = (const float*)d_in[8];  // [1024]

  float* out   = (float*)d_out;               // [32*512*1024] f32
  float* alpha = (float*)d_out + 16777216;    // [32*512*512] f32 (scores too)

  // ws: [weights 9MB][t/mix 33.5MB][cbf 33.5MB][qbf 33.5MB]
  u16* wibf_t  = (u16*)d_ws;                 // 1048576 (tile_b64 layout)
  u16* wi2bf_t = wibf_t + 1048576;           // 1048576
  u16* wobf_t  = wibf_t + 2097152;           // 524288  (tile_b layout)
  u16* wf0_t   = wibf_t + 2621440;           // 1048576
  u16* wf1_t   = wibf_t + 3670016;           // 1048576
  u16* t_ws    = (u16*)((char*)d_ws + 9437184);
  u16* cbf     = (u16*)((char*)d_ws + 42991616);
  u16* qbf     = (u16*)((char*)d_ws + 76546048);

  dim3 blk(256, 1, 1);
  dim3 blk5(512, 1, 1);

  // K0: tile/convert weights + activations
  tile_b64<<<dim3(512), blk, 0, stream>>>(W_in, 1024, 0, wibf_t, 131072);
  tile_b64<<<dim3(512), blk, 0, stream>>>(W_in2, 1024, 0, wi2bf_t, 131072);
  tile_b<<<dim3(256), blk, 0, stream>>>(W_out, 1024, 0, wobf_t, 65536);
  tile_b64<<<dim3(512), blk, 0, stream>>>(W_fc, 2048, 0, wf0_t, 131072);
  tile_b64<<<dim3(512), blk, 0, stream>>>(W_fc, 2048, 1024, wf1_t, 131072);
  cvtk<<<dim3(8192), blk, 0, stream>>>(ctx, cbf, 2097152);
  cvtk<<<dim3(8192), blk, 0, stream>>>(query, qbf, 2097152);

  // K1: t = tanh(query@W_in^T + ctx@W_in2^T + b_in + b_in2) -> bf16
  gemm_nt9<2, true, true><<<dim3(4, 64), blk5, 0, stream>>>(
      qbf, cbf, wibf_t, wi2bf_t, b_in, b_in2, t_ws, 1024);

  // K2: scores = t @ W_out^T -> f32 into alpha slot
  gemm_nt4<1, false, false><<<dim3(4, 128), blk, 0, stream>>>(
      t_ws, nullptr, 1024, wobf_t, nullptr, nullptr, nullptr, alpha, 512);

  // K3: softmax in-place
  softmax_rows_f32<<<dim3(4096), blk, 0, stream>>>(alpha);

  // K4: mix = alpha @ ctx -> bf16 (t region; t dead after K2)
  gemm_nn3<<<dim3(8, 4, 32), blk, 0, stream>>>(alpha, cbf, t_ws);

  // K5: out = mix@W_fc[:, :1024]^T + ctx@W_fc[:, 1024:]^T + b_fc -> f32
  gemm_nt9<2, false, false><<<dim3(4, 64), blk5, 0, stream>>>(
      t_ws, cbf, wf0_t, wf1_t, b_fc, nullptr, out, 1024);
}

// Round 14
// 284.429 us; speedup vs baseline: 1.2991x; 1.0052x over previous
//
#include <hip/hip_runtime.h>
#include <hip/hip_bf16.h>
#include <cstdint>

typedef unsigned short u16;
typedef unsigned int u32;
typedef __bf16 bf16x8 __attribute__((ext_vector_type(8)));
typedef float f32x4 __attribute__((ext_vector_type(4)));
typedef u16 u16x8 __attribute__((ext_vector_type(8)));

#define DEVINL __device__ __forceinline__

typedef __attribute__((address_space(1))) const u32 gbl_u32;
typedef __attribute__((address_space(3))) u32 lds_u32;

DEVINL void llds16(const void* g, void* l) {
  __builtin_amdgcn_global_load_lds((gbl_u32*)g, (lds_u32*)l, 16, 0, 0);
}

DEVINL u16 f2bf(float f) {
  union { float f; u32 i; } x; x.f = f;
  u32 r = x.i + 0x7FFFu + ((x.i >> 16) & 1u);
  return (u16)(r >> 16);
}

DEVINL float fast_tanh(float x) {
  x = fminf(10.f, fmaxf(-10.f, x));
  float e = __expf(2.f * x);
  return (e - 1.f) / (e + 1.f);
}

DEVINL bf16x8 cvt8(const float4& a, const float4& b) {
  bf16x8 r;
  r[0] = (__bf16)a.x; r[1] = (__bf16)a.y; r[2] = (__bf16)a.z; r[3] = (__bf16)a.w;
  r[4] = (__bf16)b.x; r[5] = (__bf16)b.y; r[6] = (__bf16)b.z; r[7] = (__bf16)b.w;
  return r;
}

// ---------------------------------------------------------------------------
// f32 -> bf16 convert (natural layout), 8 elems/thread
// ---------------------------------------------------------------------------
__global__ __launch_bounds__(256) void cvtk(const float* __restrict__ src,
                                            u16* __restrict__ dst, int n8) {
  int i = blockIdx.x * 256 + threadIdx.x;
  if (i >= n8) return;
  const float* s = src + (size_t)i * 8;
  *(bf16x8*)(dst + (size_t)i * 8) = cvt8(*(const float4*)s, *(const float4*)(s + 4));
}

// ---------------------------------------------------------------------------
// Weight tiler (BK=32, 128-row tiles) for gemm_nt4 (K2 / W_out).
// ---------------------------------------------------------------------------
__global__ __launch_bounds__(256) void tile_b(const float* __restrict__ src,
                                              int srcld, int koff,
                                              u16* __restrict__ dst, int nchunks) {
  int id = blockIdx.x * 256 + threadIdx.x;
  if (id >= nchunks) return;
  int n = id >> 7, k8 = id & 127;
  int kb = k8 >> 2, h = k8 & 3;
  int u = h * 128 + ((n & 127) ^ (h << 1));
  const float* s = src + (size_t)n * srcld + koff + k8 * 8;
  size_t dc = ((size_t)((n >> 7) * 32 + kb) * 512 + u) * 8;
  *(bf16x8*)(dst + dc) = cvt8(*(const float4*)s, *(const float4*)(s + 4));
}

// ---------------------------------------------------------------------------
// Weight tiler (BK=64, 256-row tiles) for gemm_nt10 B-side.
// chunk (n, h=k8&7): unit = h*256 + ((n&255) ^ (h<<1)); tile = (n>>8)*16 + kb
// ---------------------------------------------------------------------------
__global__ __launch_bounds__(256) void tile_b64(const float* __restrict__ src,
                                                int srcld, int koff,
                                                u16* __restrict__ dst, int nchunks) {
  int id = blockIdx.x * 256 + threadIdx.x;
  if (id >= nchunks) return;
  int n = id >> 7, k8 = id & 127;
  int kb = k8 >> 3, h = k8 & 7;
  int u = h * 256 + ((n & 255) ^ (h << 1));
  const float* s = src + (size_t)n * srcld + koff + k8 * 8;
  size_t dc = ((size_t)((n >> 8) * 16 + kb) * 2048 + u) * 8;
  *(bf16x8*)(dst + dc) = cvt8(*(const float4*)s, *(const float4*)(s + 4));
}

// ---------------------------------------------------------------------------
// gemm_nt10: 256x256, BK=64, 8 waves (2Mx4N), all-bf16, gll staging.
// m201-FAITHFUL phase microstructure: per tile, 4 phases of
//   { ds_reads ; stage-issue ; [vmcnt guard] ; s_barrier ;
//     lgkmcnt(0)+sched_barrier ; setprio(1) ; 16 MFMA ; setprio(0) }
// Reads issue BEFORE the barrier -> LDS latency overlaps rendezvous.
// Guards merged into phase-closing barriers: P1 end vmcnt(8) (B q23[t]),
// P3 end vmcnt(6) (A[t+1]+B[t+1]q01). A triple-buffered, B double.
// Stage slices: P0/P1 = B[t+1] q01/q23; P2/P3 = A[t+2] q01/q23.
// A map (coalesced src, even-bank read): unit u <-> (row=u>>3,
// oct=(u&7)^(row&7)). B: pre-tiled (tile_b64), contiguous 1KB per gll.
// ---------------------------------------------------------------------------
template <int NSEG, bool OUT_BF16, bool TANH>
__global__ __launch_bounds__(512) void gemm_nt10(
    const u16* __restrict__ A0, const u16* __restrict__ A1,
    const u16* __restrict__ Bt0, const u16* __restrict__ Bt1,
    const float* __restrict__ bias0, const float* __restrict__ bias1,
    void* __restrict__ Cout, int ldc) {
  __shared__ u16 As[3][16384];
  __shared__ u16 Bs[2][16384];
  const int tid = threadIdx.x, lane = tid & 63, w = tid >> 6;
  const int wr = w >> 2, wc = w & 3;

  // XCD-bijective swizzle (total % 8 == 0)
  const int NX = gridDim.x;
  const int total = NX * gridDim.y;
  const int flat = blockIdx.y * NX + blockIdx.x;
  const int wid = (flat & 7) * (total >> 3) + (flat >> 3);
  const int nb = wid % NX;
  const int n0 = nb * 256, m0 = (wid / NX) * 256;

  f32x4 acc[8][4];
#pragma unroll
  for (int i = 0; i < 8; ++i)
#pragma unroll
    for (int j = 0; j < 4; ++j) acc[i][j] = (f32x4)0.f;

  // staging maps (quarter q = units [q*512, q*512+512))
  u32 asrc[4], bofs[4];
#pragma unroll
  for (int r = 0; r < 4; ++r) {
    int u = r * 512 + w * 64 + lane;
    int row = u >> 3, oct = (u & 7) ^ (row & 7);
    asrc[r] = (u32)(m0 + row) * 1024u + (u32)(oct * 8);
    bofs[r] = (u32)u * 8u;
  }

  const int NT = NSEG * 16;

  auto stageA = [&](int t) {  // 4 glls into As[t%3]
    const int seg = (NSEG == 2 && t >= 16) ? 1 : 0;
    const int kb = t - (seg << 4);
    const u16* Ap = seg ? A1 : A0;
    const u32 k0 = (u32)(kb << 6);
    u16* dst = As[t % 3];
#pragma unroll
    for (int q = 0; q < 4; ++q)
      llds16(Ap + (size_t)(asrc[q] + k0), dst + (q * 512 + w * 64) * 8);
  };
  auto stageA2 = [&](int t, int rp) {  // quarters 2rp,2rp+1 into As[t%3]
    const int seg = (NSEG == 2 && t >= 16) ? 1 : 0;
    const int kb = t - (seg << 4);
    const u16* Ap = seg ? A1 : A0;
    const u32 k0 = (u32)(kb << 6);
    u16* dst = As[t % 3];
#pragma unroll
    for (int r = 0; r < 2; ++r) {
      const int q = rp * 2 + r;
      llds16(Ap + (size_t)(asrc[q] + k0), dst + (q * 512 + w * 64) * 8);
    }
  };
  auto stageB = [&](int t) {  // 4 glls into Bs[t&1]
    const int seg = (NSEG == 2 && t >= 16) ? 1 : 0;
    const int kb = t - (seg << 4);
    const u16* Bt = (seg ? Bt1 : Bt0) + ((size_t)(nb * 16 + kb) << 14);
    u16* dst = Bs[t & 1];
#pragma unroll
    for (int q = 0; q < 4; ++q)
      llds16(Bt + (size_t)bofs[q], dst + (q * 512 + w * 64) * 8);
  };
  auto stageB2 = [&](int t, int rp) {
    const int seg = (NSEG == 2 && t >= 16) ? 1 : 0;
    const int kb = t - (seg << 4);
    const u16* Bt = (seg ? Bt1 : Bt0) + ((size_t)(nb * 16 + kb) << 14);
    u16* dst = Bs[t & 1];
#pragma unroll
    for (int r = 0; r < 2; ++r) {
      const int q = rp * 2 + r;
      llds16(Bt + (size_t)bofs[q], dst + (q * 512 + w * 64) * 8);
    }
  };

  // prologue: A0(4), B0(4), A1(4); guard A0+B0q01 then barrier
  stageA(0);
  stageB(0);
  if (NT > 1) stageA(1);
  asm volatile("s_waitcnt vmcnt(6)" ::: "memory");
  __builtin_amdgcn_s_barrier();

  const int rl = lane & 15;
  for (int t = 0; t < NT; ++t) {
    const int ab = t % 3, bb = t & 1;
    const bool preB = (t + 1 < NT);
    const bool preA = (t + 2 < NT);
    bf16x8 af[8];

    // ======== P0: reads(af kh0 + bv j01) ; stage B[t+1]q01 ; bar ; MFMA
    {
      const int h = lane >> 4;
      const int jA = h ^ (rl & 7);
#pragma unroll
      for (int i = 0; i < 8; ++i)
        af[i] = *(const bf16x8*)&As[ab][((wr * 128 + i * 16 + rl) * 8 + jA) * 8];
      bf16x8 b0 = *(const bf16x8*)&Bs[bb][(h * 256 + ((wc * 64 + 0 + rl) ^ (h << 1))) * 8];
      bf16x8 b1 = *(const bf16x8*)&Bs[bb][(h * 256 + ((wc * 64 + 16 + rl) ^ (h << 1))) * 8];
      if (preB) stageB2(t + 1, 0);
      __builtin_amdgcn_s_barrier();
      asm volatile("s_waitcnt lgkmcnt(0)" ::: "memory");
      __builtin_amdgcn_sched_barrier(0);
      __builtin_amdgcn_s_setprio(1);
#pragma unroll
      for (int i = 0; i < 8; ++i) {
        acc[i][0] = __builtin_amdgcn_mfma_f32_16x16x32_bf16(af[i], b0, acc[i][0], 0, 0, 0);
        acc[i][1] = __builtin_amdgcn_mfma_f32_16x16x32_bf16(af[i], b1, acc[i][1], 0, 0, 0);
      }
      __builtin_amdgcn_s_setprio(0);
    }
    // ======== P1: reads(bv j23) ; stage B[t+1]q23 ; GUARD vmcnt(8) ; bar
    {
      const int h = lane >> 4;
      bf16x8 b2 = *(const bf16x8*)&Bs[bb][(h * 256 + ((wc * 64 + 32 + rl) ^ (h << 1))) * 8];
      bf16x8 b3 = *(const bf16x8*)&Bs[bb][(h * 256 + ((wc * 64 + 48 + rl) ^ (h << 1))) * 8];
      if (preB) stageB2(t + 1, 1);
      if (preB) asm volatile("s_waitcnt vmcnt(8)" ::: "memory");
      else      asm volatile("s_waitcnt vmcnt(0)" ::: "memory");
      __builtin_amdgcn_s_barrier();
      asm volatile("s_waitcnt lgkmcnt(0)" ::: "memory");
      __builtin_amdgcn_sched_barrier(0);
      __builtin_amdgcn_s_setprio(1);
#pragma unroll
      for (int i = 0; i < 8; ++i) {
        acc[i][2] = __builtin_amdgcn_mfma_f32_16x16x32_bf16(af[i], b2, acc[i][2], 0, 0, 0);
        acc[i][3] = __builtin_amdgcn_mfma_f32_16x16x32_bf16(af[i], b3, acc[i][3], 0, 0, 0);
      }
      __builtin_amdgcn_s_setprio(0);
    }
    // ======== P2: reads(af kh1 + bv j01) ; stage A[t+2]q01 ; bar ; MFMA
    {
      const int h = 4 + (lane >> 4);
      const int jA = h ^ (rl & 7);
#pragma unroll
      for (int i = 0; i < 8; ++i)
        af[i] = *(const bf16x8*)&As[ab][((wr * 128 + i * 16 + rl) * 8 + jA) * 8];
      bf16x8 b0 = *(const bf16x8*)&Bs[bb][(h * 256 + ((wc * 64 + 0 + rl) ^ (h << 1))) * 8];
      bf16x8 b1 = *(const bf16x8*)&Bs[bb][(h * 256 + ((wc * 64 + 16 + rl) ^ (h << 1))) * 8];
      if (preA) stageA2(t + 2, 0);
      __builtin_amdgcn_s_barrier();
      asm volatile("s_waitcnt lgkmcnt(0)" ::: "memory");
      __builtin_amdgcn_sched_barrier(0);
      __builtin_amdgcn_s_setprio(1);
#pragma unroll
      for (int i = 0; i < 8; ++i) {
        acc[i][0] = __builtin_amdgcn_mfma_f32_16x16x32_bf16(af[i], b0, acc[i][0], 0, 0, 0);
        acc[i][1] = __builtin_amdgcn_mfma_f32_16x16x32_bf16(af[i], b1, acc[i][1], 0, 0, 0);
      }
      __builtin_amdgcn_s_setprio(0);
    }
    // ======== P3: reads(bv j23) ; stage A[t+2]q23 ; GUARD vmcnt(6) ; bar
    {
      const int h = 4 + (lane >> 4);
      bf16x8 b2 = *(const bf16x8*)&Bs[bb][(h * 256 + ((wc * 64 + 32 + rl) ^ (h << 1))) * 8];
      bf16x8 b3 = *(const bf16x8*)&Bs[bb][(h * 256 + ((wc * 64 + 48 + rl) ^ (h << 1))) * 8];
      if (preA) stageA2(t + 2, 1);
      if (t < NT - 2)       asm volatile("s_waitcnt vmcnt(6)" ::: "memory");
      else if (t == NT - 2) asm volatile("s_waitcnt vmcnt(2)" ::: "memory");
      else                  asm volatile("s_waitcnt vmcnt(0)" ::: "memory");
      __builtin_amdgcn_s_barrier();
      asm volatile("s_waitcnt lgkmcnt(0)" ::: "memory");
      __builtin_amdgcn_sched_barrier(0);
      __builtin_amdgcn_s_setprio(1);
#pragma unroll
      for (int i = 0; i < 8; ++i) {
        acc[i][2] = __builtin_amdgcn_mfma_f32_16x16x32_bf16(af[i], b2, acc[i][2], 0, 0, 0);
        acc[i][3] = __builtin_amdgcn_mfma_f32_16x16x32_bf16(af[i], b3, acc[i][3], 0, 0, 0);
      }
      __builtin_amdgcn_s_setprio(0);
    }
  }

  // Epilogue. C/D: col = lane&15, row = (lane>>4)*4 + reg.
  const int rq = lane >> 4;
#pragma unroll
  for (int j = 0; j < 4; ++j) {
    const int gc = n0 + wc * 64 + j * 16 + rl;
    float bia = 0.f;
    if (bias0) bia += bias0[gc];
    if (NSEG == 2 && bias1) bia += bias1[gc];
#pragma unroll
    for (int i = 0; i < 8; ++i) {
#pragma unroll
      for (int r = 0; r < 4; ++r) {
        const int grow = m0 + wr * 128 + i * 16 + rq * 4 + r;
        float v = acc[i][j][r] + bia;
        if (TANH) v = fast_tanh(v);
        if (OUT_BF16)
          ((u16*)Cout)[(size_t)grow * ldc + gc] = f2bf(v);
        else
          ((float*)Cout)[(size_t)grow * ldc + gc] = v;
      }
    }
  }
}

// ---------------------------------------------------------------------------
// gemm_nt4: 128x128/BK=32 all-bf16 (K2 only). R10/R11 version.
// ---------------------------------------------------------------------------
template <int NSEG, bool OUT_BF16, bool TANH>
__global__ __launch_bounds__(256) void gemm_nt4(
    const u16* __restrict__ A0, const u16* __restrict__ A1, int lda,
    const u16* __restrict__ Bt0, const u16* __restrict__ Bt1,
    const float* __restrict__ bias0, const float* __restrict__ bias1,
    void* __restrict__ Cout, int ldc) {
  __shared__ u16 As[2][4096];
  __shared__ u16 Bs[2][4096];
  const int tid = threadIdx.x, lane = tid & 63, w = tid >> 6;
  const int wr = w >> 1, wc = w & 1;
  const int NX = gridDim.x;
  const int total = NX * gridDim.y;
  const int flat = blockIdx.y * NX + blockIdx.x;
  const int wid = (flat & 7) * (total >> 3) + (flat >> 3);
  const int nb = wid % NX;
  const int n0 = nb * 128, m0 = (wid / NX) * 128;
  const int h = lane >> 4, rl = lane & 15;
  const int jA = h ^ (rl & 3);

  f32x4 acc[4][4];
#pragma unroll
  for (int i = 0; i < 4; ++i)
#pragma unroll
    for (int j = 0; j < 4; ++j) acc[i][j] = (f32x4)0.f;

  const int gb0 = w * 64, gb1 = 256 + w * 64;
  u32 asrc[2];
  {
    int u0 = gb0 + lane, u1 = gb1 + lane;
    int r0 = u0 >> 2, o0 = (u0 & 3) ^ (r0 & 3);
    int r1 = u1 >> 2, o1 = (u1 & 3) ^ (r1 & 3);
    asrc[0] = (u32)(m0 + r0) * (u32)lda + (u32)(o0 * 8);
    asrc[1] = (u32)(m0 + r1) * (u32)lda + (u32)(o1 * 8);
  }
  const int NT = NSEG * 32;

  auto stage = [&](int t, int buf) {
    const int seg = (NSEG == 2 && t >= 32) ? 1 : 0;
    const int kb = t - seg * 32, kl = kb << 5;
    {
      const u16* Bt = (seg ? Bt1 : Bt0) + ((size_t)(nb * 32 + kb) * 512) * 8;
      llds16(Bt + (size_t)(gb0 + lane) * 8, &Bs[buf][gb0 * 8]);
      llds16(Bt + (size_t)(gb1 + lane) * 8, &Bs[buf][gb1 * 8]);
    }
    {
      const u16* Ap = seg ? A1 : A0;
      llds16(Ap + (size_t)(asrc[0] + kl), &As[buf][gb0 * 8]);
      llds16(Ap + (size_t)(asrc[1] + kl), &As[buf][gb1 * 8]);
    }
  };
  auto compute = [&](int buf) {
    bf16x8 af[4], bfv[4];
#pragma unroll
    for (int i = 0; i < 4; ++i)
      af[i] = *(const bf16x8*)&As[buf][((wr * 64 + i * 16 + rl) * 4 + jA) * 8];
#pragma unroll
    for (int j = 0; j < 4; ++j)
      bfv[j] = *(const bf16x8*)&Bs[buf][(h * 128 + ((wc * 64 + j * 16 + rl) ^ (h << 1))) * 8];
#pragma unroll
    for (int i = 0; i < 4; ++i)
#pragma unroll
      for (int j = 0; j < 4; ++j)
        acc[i][j] =
            __builtin_amdgcn_mfma_f32_16x16x32_bf16(af[i], bfv[j], acc[i][j], 0, 0, 0);
  };

  stage(0, 0);
  for (int t = 0; t < NT; ++t) {
    const int c = t & 1;
    if (t + 1 < NT) {
      stage(t + 1, c ^ 1);
      asm volatile("s_waitcnt vmcnt(4)" ::: "memory");
    } else {
      asm volatile("s_waitcnt vmcnt(0)" ::: "memory");
    }
    __builtin_amdgcn_s_barrier();
    __builtin_amdgcn_sched_barrier(0);
    compute(c);
    __builtin_amdgcn_s_barrier();
  }

  const int rq = lane >> 4;
#pragma unroll
  for (int j = 0; j < 4; ++j) {
    const int gc = n0 + wc * 64 + j * 16 + rl;
    float bia = 0.f;
    if (bias0) bia += bias0[gc];
    if (NSEG == 2 && bias1) bia += bias1[gc];
#pragma unroll
    for (int i = 0; i < 4; ++i) {
#pragma unroll
      for (int r = 0; r < 4; ++r) {
        const int grow = m0 + wr * 64 + i * 16 + rq * 4 + r;
        float v = acc[i][j][r] + bia;
        if (TANH) v = fast_tanh(v);
        if (OUT_BF16)
          ((u16*)Cout)[(size_t)grow * ldc + gc] = f2bf(v);
        else
          ((float*)Cout)[(size_t)grow * ldc + gc] = v;
      }
    }
  }
}

// ---------------------------------------------------------------------------
// NN GEMM (per batch): mix[l,d] = sum_w alpha[l,w]*ctx_bf[w,d]; K=512.
// ---------------------------------------------------------------------------
__global__ __launch_bounds__(256) void gemm_nn3(
    const float* __restrict__ alpha, const u16* __restrict__ ctxb,
    u16* __restrict__ mix) {
  __shared__ u16 As[2][4096];
  __shared__ u16 Bs[2][4096];
  const int tid = threadIdx.x, lane = tid & 63, w = tid >> 6;
  const int wr = w >> 1, wc = w & 1;
  const int b = blockIdx.z;
  const int n0 = blockIdx.x * 128, m0 = blockIdx.y * 128;
  const int h = lane >> 4, rlx = (lane & 15) ^ (h << 1);
  const float* A = alpha + (size_t)b * 262144;
  u16* C = mix + (size_t)b * 524288;

  f32x4 acc[4][4];
#pragma unroll
  for (int i = 0; i < 4; ++i)
#pragma unroll
    for (int j = 0; j < 4; ++j) acc[i][j] = (f32x4)0.f;

  const int row0 = tid >> 2, cb = tid & 3, row1 = 64 + row0;
  const int unit0 = cb * 128 + (row0 ^ (cb << 1));
  const int unit1 = cb * 128 + (row1 ^ (cb << 1));
  const int kl = tid & 31, ng = tid >> 5;
  const int hb = kl >> 3, kp = kl & 7;

  float4 fr[4];
  u16x8 ub[2];

  auto stage = [&](int t) {
    const int k0 = t << 5;
    const float* p0 = A + (size_t)(m0 + row0) * 512 + k0 + cb * 8;
    const float* p1 = A + (size_t)(m0 + row1) * 512 + k0 + cb * 8;
    fr[0] = *(const float4*)p0; fr[1] = *(const float4*)(p0 + 4);
    fr[2] = *(const float4*)p1; fr[3] = *(const float4*)(p1 + 4);
    const u16* Cb = ctxb + (size_t)b * 524288 + (size_t)(k0 + kl) * 1024 +
                    n0 + ng * 16;
    ub[0] = *(const u16x8*)Cb; ub[1] = *(const u16x8*)(Cb + 8);
  };
  auto stage_fin = [&](int buf) {
    *(bf16x8*)&As[buf][unit0 * 8] = cvt8(fr[0], fr[1]);
    *(bf16x8*)&As[buf][unit1 * 8] = cvt8(fr[2], fr[3]);
#pragma unroll
    for (int j = 0; j < 16; ++j) {
      int n = ng * 16 + j;
      Bs[buf][(hb * 128 + (n ^ (hb << 1))) * 8 + kp] =
          (j < 8) ? ub[0][j] : ub[1][j - 8];
    }
  };
  auto compute = [&](int buf) {
    bf16x8 af[4], bfv[4];
#pragma unroll
    for (int i = 0; i < 4; ++i)
      af[i] = *(const bf16x8*)&As[buf][(h * 128 + wr * 64 + i * 16 + rlx) * 8];
#pragma unroll
    for (int j = 0; j < 4; ++j)
      bfv[j] = *(const bf16x8*)&Bs[buf][(h * 128 + wc * 64 + j * 16 + rlx) * 8];
#pragma unroll
    for (int i = 0; i < 4; ++i)
#pragma unroll
      for (int j = 0; j < 4; ++j)
        acc[i][j] =
            __builtin_amdgcn_mfma_f32_16x16x32_bf16(af[i], bfv[j], acc[i][j], 0, 0, 0);
  };

  stage(0);
  stage_fin(0);
  __syncthreads();
  for (int t = 0; t < 16; ++t) {
    const int cb_ = t & 1;
    if (t + 1 < 16) stage(t + 1);
    compute(cb_);
    if (t + 1 < 16) stage_fin(cb_ ^ 1);
    __syncthreads();
  }

  const int rl = lane & 15, rq = lane >> 4;
#pragma unroll
  for (int j = 0; j < 4; ++j) {
    const int gc = n0 + wc * 64 + j * 16 + rl;
#pragma unroll
    for (int i = 0; i < 4; ++i) {
#pragma unroll
      for (int r = 0; r < 4; ++r) {
        const int grow = m0 + wr * 64 + i * 16 + rq * 4 + r;
        C[(size_t)grow * 1024 + gc] = f2bf(acc[i][j][r]);
      }
    }
  }
}

// ---------------------------------------------------------------------------
// Row softmax, in-place f32: one wave per row of 512
// ---------------------------------------------------------------------------
__global__ __launch_bounds__(256) void softmax_rows_f32(float* __restrict__ S) {
  const int row = blockIdx.x * 4 + (threadIdx.x >> 6);
  const int lane = threadIdx.x & 63;
  float* s = S + (size_t)row * 512 + lane * 8;
  float4 v0 = *(const float4*)s;
  float4 v1 = *(const float4*)(s + 4);
  float vs[8] = {v0.x, v0.y, v0.z, v0.w, v1.x, v1.y, v1.z, v1.w};
  float vm = vs[0];
#pragma unroll
  for (int j = 1; j < 8; ++j) vm = fmaxf(vm, vs[j]);
#pragma unroll
  for (int off = 32; off > 0; off >>= 1) vm = fmaxf(vm, __shfl_xor(vm, off, 64));
  float e[8];
  float sum = 0.f;
#pragma unroll
  for (int j = 0; j < 8; ++j) { e[j] = __expf(vs[j] - vm); sum += e[j]; }
#pragma unroll
  for (int off = 32; off > 0; off >>= 1) sum += __shfl_xor(sum, off, 64);
  float inv = 1.f / sum;
  float4 o0 = {e[0] * inv, e[1] * inv, e[2] * inv, e[3] * inv};
  float4 o1 = {e[4] * inv, e[5] * inv, e[6] * inv, e[7] * inv};
  *(float4*)s = o0;
  *(float4*)(s + 4) = o1;
}

// ---------------------------------------------------------------------------
extern "C" void kernel_launch(void* const* d_in, const int* in_sizes, int n_in,
                              void* d_out, int out_size, void* d_ws, size_t ws_size,
                              hipStream_t stream) {
  const float* query = (const float*)d_in[0];  // [32,512,1024] f32
  const float* ctx   = (const float*)d_in[1];  // [32,512,1024]
  const float* W_in  = (const float*)d_in[2];  // [1024,1024]
  const float* b_in  = (const float*)d_in[3];  // [1024]
  const float* W_in2 = (const float*)d_in[4];  // [1024,1024]
  const float* b_in2 = (const float*)d_in[5];  // [1024]
  const float* W_out = (const float*)d_in[6];  // [512,1024]
  const float* W_fc  = (const float*)d_in[7];  // [1024,2048]
  const float* b_fc  = (const float*)d_in[8];  // [1024]

  float* out   = (float*)d_out;               // [32*512*1024] f32
  float* alpha = (float*)d_out + 16777216;    // [32*512*512] f32 (scores too)

  // ws: [weights 9MB][t/mix 33.5MB][cbf 33.5MB][qbf 33.5MB]
  u16* wibf_t  = (u16*)d_ws;                 // 1048576 (tile_b64 layout)
  u16* wi2bf_t = wibf_t + 1048576;           // 1048576
  u16* wobf_t  = wibf_t + 2097152;           // 524288  (tile_b layout)
  u16* wf0_t   = wibf_t + 2621440;           // 1048576
  u16* wf1_t   = wibf_t + 3670016;           // 1048576
  u16* t_ws    = (u16*)((char*)d_ws + 9437184);
  u16* cbf     = (u16*)((char*)d_ws + 42991616);
  u16* qbf     = (u16*)((char*)d_ws + 76546048);

  dim3 blk(256, 1, 1);
  dim3 blk5(512, 1, 1);

  // K0: tile/convert weights + activations
  tile_b64<<<dim3(512), blk, 0, stream>>>(W_in, 1024, 0, wibf_t, 131072);
  tile_b64<<<dim3(512), blk, 0, stream>>>(W_in2, 1024, 0, wi2bf_t, 131072);
  tile_b<<<dim3(256), blk, 0, stream>>>(W_out, 1024, 0, wobf_t, 65536);
  tile_b64<<<dim3(512), blk, 0, stream>>>(W_fc, 2048, 0, wf0_t, 131072);
  tile_b64<<<dim3(512), blk, 0, stream>>>(W_fc, 2048, 1024, wf1_t, 131072);
  cvtk<<<dim3(8192), blk, 0, stream>>>(ctx, cbf, 2097152);
  cvtk<<<dim3(8192), blk, 0, stream>>>(query, qbf, 2097152);

  // K1: t = tanh(query@W_in^T + ctx@W_in2^T + b_in + b_in2) -> bf16
  gemm_nt10<2, true, true><<<dim3(4, 64), blk5, 0, stream>>>(
      qbf, cbf, wibf_t, wi2bf_t, b_in, b_in2, t_ws, 1024);

  // K2: scores = t @ W_out^T -> f32 into alpha slot
  gemm_nt4<1, false, false><<<dim3(4, 128), blk, 0, stream>>>(
      t_ws, nullptr, 1024, wobf_t, nullptr, nullptr, nullptr, alpha, 512);

  // K3: softmax in-place
  softmax_rows_f32<<<dim3(4096), blk, 0, stream>>>(alpha);

  // K4: mix = alpha @ ctx -> bf16 (t region; t dead after K2)
  gemm_nn3<<<dim3(8, 4, 32), blk, 0, stream>>>(alpha, cbf, t_ws);

  // K5: out = mix@W_fc[:, :1024]^T + ctx@W_fc[:, 1024:]^T + b_fc -> f32
  gemm_nt10<2, false, false><<<dim3(4, 64), blk5, 0, stream>>>(
      t_ws, cbf, wf0_t, wf1_t, b_fc, nullptr, out, 1024);
}